// Round 5
// baseline (1211.513 us; speedup 1.0000x reference)
//
#include <hip/hip_runtime.h>

// B=4, N=M=4096, D=128.
// d_out (floats): match_mask [4*4096*4096] | pairs [16384] (as float) | top_dists [16384]
// ws fast path:
//   bytes [0, 131072):        x2 [16384] f32 | y2 [16384] f32
//   bytes [131072, 25296896): planes, 6 x PS elems bf16 (x:h,m,l then y:h,m,l)
//     chunk layout: [b(4)][kh(2)][rt(32)] -> 8192-elem (16 KiB) chunk
//     within chunk: [rb(8)][kc(2)][lane(64)][e(8)], value = in[b][rt*128+rb*16+(l&15)][kh*64+kc*32+(l>>4)*8+e]
//   bytes [25296896, 25821184): pv [16384*4] f32 | pi [16384*4] i32
// Extended-K: 6 plane products = K=768 bf16 GEMM, A segs [h,h,m,m,h,l], B segs [h,m,h,m,l,h].

typedef float  f32x4  __attribute__((ext_vector_type(4)));
typedef short  bf16x8 __attribute__((ext_vector_type(8)));

#define PS ((size_t)2097152)

#define WAITVM_(N) asm volatile("s_waitcnt vmcnt(" #N ")" ::: "memory")
#define WAITVM(N)  WAITVM_(N)
#define LGKM0      asm volatile("s_waitcnt lgkmcnt(0)" ::: "memory")

__device__ __forceinline__ unsigned short f2bf(float x) {
    unsigned u = __float_as_uint(x);
    u += 0x7FFFu + ((u >> 16) & 1u);
    return (unsigned short)(u >> 16);
}
__device__ __forceinline__ float bf2f(unsigned short s) {
    return __uint_as_float(((unsigned)s) << 16);
}
__device__ __forceinline__ void gload_lds16(const void* g, void* l) {
    __builtin_amdgcn_global_load_lds(
        (const __attribute__((address_space(1))) void*)g,
        (__attribute__((address_space(3))) void*)l, 16, 0, 0);
}

// ---- split f32 -> 3 bf16 planes (fragment order) + fused row sum-of-squares ----
__global__ __launch_bounds__(256) void k_prep(const float* __restrict__ xd,
                                              const float* __restrict__ yd,
                                              unsigned short* __restrict__ pl,
                                              float* __restrict__ ws) {
    __shared__ float sm[4][16];
    int bid  = blockIdx.x;            // 0..2047
    int i    = bid >> 10;
    int b    = (bid >> 8) & 3;
    int rblk = bid & 255;
    int tid  = threadIdx.x;
    int kb   = tid >> 6;
    int l    = tid & 63;
    int r    = rblk * 16 + (l & 15);
    int k0   = kb * 32 + ((l >> 4) & 3) * 8;
    const float* src = (i ? yd : xd) + ((size_t)(b * 4096 + r) * 128 + k0);
    float v[8];
    *reinterpret_cast<float4*>(v)     = *reinterpret_cast<const float4*>(src);
    *reinterpret_cast<float4*>(v + 4) = *reinterpret_cast<const float4*>(src + 4);
    bf16x8 hv, mv, lv;
    float s = 0.f;
    #pragma unroll
    for (int e = 0; e < 8; ++e) {
        float x = v[e];
        s = fmaf(x, x, s);
        unsigned short h  = f2bf(x);
        float r1 = x - bf2f(h);
        unsigned short m  = f2bf(r1);
        float r2 = r1 - bf2f(m);
        unsigned short lo = f2bf(r2);
        hv[e] = (short)h; mv[e] = (short)m; lv[e] = (short)lo;
    }
    int rt = rblk >> 3, rb = rblk & 7, kh = kb >> 1, kc = kb & 1;
    size_t base = ((((size_t)((b * 2 + kh) * 32 + rt)) * 8 + rb) * 2 + kc) * 512 + (size_t)l * 8;
    unsigned short* dst = pl + (size_t)(i * 3) * PS;
    *reinterpret_cast<bf16x8*>(dst + base)          = hv;
    *reinterpret_cast<bf16x8*>(dst + base + PS)     = mv;
    *reinterpret_cast<bf16x8*>(dst + base + 2 * PS) = lv;
    // row sum-of-squares: sum over (l>>4) groups then over kb
    s += __shfl_xor(s, 16);
    s += __shfl_xor(s, 32);
    if (l < 16) sm[kb][l] = s;
    __syncthreads();
    if (tid < 16) {
        float t = sm[0][tid] + sm[1][tid] + sm[2][tid] + sm[3][tid];
        ws[(i ? 16384 : 0) + b * 4096 + rblk * 16 + tid] = t;
    }
}

// ---- main: deep-pipelined (counted vmcnt) extended-K bf16 GEMM + fused epilogue ----
__global__ __launch_bounds__(256, 2) void k_gemm(const float* __restrict__ mask,
                                                 const float* __restrict__ ws,
                                                 const unsigned short* __restrict__ pl,
                                                 float* __restrict__ out,
                                                 float* __restrict__ pv,
                                                 int* __restrict__ pi) {
    __shared__ __align__(16) unsigned short Abuf[2][8192];
    __shared__ __align__(16) unsigned short Bbuf[2][8192];
    __shared__ float candv[128][2];
    __shared__ int   candi[128][2];

    const int bid = blockIdx.x;        // 512 blocks = 2/CU
    const int xcd = bid & 7;
    const int j   = bid >> 3;
    const int b   = xcd >> 1;
    const int rt  = (xcd & 1) * 16 + (j >> 2);
    const int cq  = j & 3;
    const int tid = threadIdx.x;
    const int w   = tid >> 6, l = tid & 63;
    const int wr  = w >> 1, wc = w & 1;
    const int g0  = b * 4096 + rt * 128;
    const int col0 = cq * 1024;

    const float* y2 = ws + 16384 + b * 4096;
    float x2r[16];
    #pragma unroll
    for (int mi = 0; mi < 4; ++mi)
        #pragma unroll
        for (int rg = 0; rg < 4; ++rg)
            x2r[mi * 4 + rg] = ws[g0 + wr * 64 + mi * 16 + ((l >> 4) & 3) * 4 + rg];

    float bv[16];
    int   bi[16];
    #pragma unroll
    for (int q = 0; q < 16; ++q) { bv[q] = 3.4e38f; bi[q] = 0; }

    f32x4 acc[4][4];
    float pm[32];   // prefetched mask for mi=0,1 (all indices compile-time)

    auto stage = [&](int ntS, int sA, int sB, int kh, int bsel) {
        const unsigned short* Ac = pl + (size_t)sA * PS
            + (((size_t)((b * 2 + kh) * 32 + rt)) << 13);
        const unsigned short* Bc = pl + (size_t)(3 + sB) * PS
            + (((size_t)((b * 2 + kh) * 32 + (cq * 8 + ntS))) << 13);
        const char* gA = (const char*)Ac + (size_t)(w * 1024 + l * 16);
        const char* gB = (const char*)Bc + (size_t)(w * 1024 + l * 16);
        char* lA = (char*)(&Abuf[bsel][0]) + w * 1024;
        char* lB = (char*)(&Bbuf[bsel][0]) + w * 1024;
        _Pragma("unroll")
        for (int it = 0; it < 4; ++it) {
            gload_lds16(gA + it * 4096, lA + it * 4096);
            gload_lds16(gB + it * 4096, lB + it * 4096);
        }
    };

    // prologue: steps (0,0)->buf0, (0,1)->buf1
    stage(0, 0, 0, 0, 0);
    stage(0, 0, 0, 1, 1);
    WAITVM(8);
    __builtin_amdgcn_s_barrier();

#define SA_(seg) ((seg) == 5 ? 2 : (((seg) == 2 || (seg) == 3) ? 1 : 0))
#define SB_(seg) ((seg) == 4 ? 2 : (((seg) == 1 || (seg) == 3) ? 1 : 0))

#define PHASE(S, IS) do {                                                        \
    /* ---- slot1: compute ---- */                                               \
    if (S == 0) {                                                                \
        _Pragma("unroll") for (int mi = 0; mi < 4; ++mi)                         \
        _Pragma("unroll") for (int ni = 0; ni < 4; ++ni)                         \
            acc[mi][ni] = (f32x4){0.f, 0.f, 0.f, 0.f};                           \
    }                                                                            \
    {                                                                            \
        bf16x8 af[4][2], bfr[4][2];                                              \
        _Pragma("unroll") for (int mi = 0; mi < 4; ++mi)                         \
        _Pragma("unroll") for (int kc = 0; kc < 2; ++kc)                         \
            af[mi][kc] = *reinterpret_cast<const bf16x8*>(                       \
                &Abuf[S & 1][(((wr * 4 + mi) * 2 + kc) * 512) + l * 8]);         \
        _Pragma("unroll") for (int ni = 0; ni < 4; ++ni)                         \
        _Pragma("unroll") for (int kc = 0; kc < 2; ++kc)                         \
            bfr[ni][kc] = *reinterpret_cast<const bf16x8*>(                      \
                &Bbuf[S & 1][(((wc * 4 + ni) * 2 + kc) * 512) + l * 8]);         \
        __builtin_amdgcn_s_setprio(1);                                           \
        _Pragma("unroll") for (int kc = 0; kc < 2; ++kc)                         \
        _Pragma("unroll") for (int mi = 0; mi < 4; ++mi)                         \
        _Pragma("unroll") for (int ni = 0; ni < 4; ++ni)                         \
            acc[mi][ni] = __builtin_amdgcn_mfma_f32_16x16x32_bf16(               \
                af[mi][kc], bfr[ni][kc], acc[mi][ni], 0, 0, 0);                  \
        __builtin_amdgcn_s_setprio(0);                                           \
    }                                                                            \
    if (S == 11) {                                                               \
        _Pragma("unroll") for (int ni = 0; ni < 4; ++ni) {                       \
            int c = col0 + nt * 128 + wc * 64 + ni * 16 + (l & 15);              \
            float y2v = y2[c];                                                   \
            _Pragma("unroll") for (int mi = 0; mi < 4; ++mi)                     \
            _Pragma("unroll") for (int rg = 0; rg < 4; ++rg) {                   \
                int grow = g0 + wr * 64 + mi * 16 + ((l >> 4) & 3) * 4 + rg;     \
                float mval = (mi < 2) ? pm[mi * 16 + rg * 4 + ni]                \
                    : __builtin_nontemporal_load(mask + (size_t)grow * 4096 + c);\
                float d2 = x2r[mi * 4 + rg] + y2v - 2.0f * acc[mi][ni][rg];      \
                float d  = sqrtf(fmaxf(d2, 0.0f)) * mval;                        \
                int q = mi * 4 + rg;                                             \
                if (d < bv[q]) { bv[q] = d; bi[q] = c; }                         \
            }                                                                    \
        }                                                                        \
    }                                                                            \
    LGKM0;                                                                       \
    __builtin_amdgcn_s_barrier();                                                \
    /* ---- slot3: issue next-next stage + mask prefetch + zero stores ---- */   \
    if (S <= 9)        stage(nt,     SA_((S + 2) >> 1), SB_((S + 2) >> 1),       \
                             (S + 2) & 1, S & 1);                                \
    else if (!last)    stage(nt + 1, 0, 0, S - 10, S & 1);                       \
    if (S >= 1 && S <= 4) {                                                      \
        _Pragma("unroll") for (int k = 0; k < 8; ++k) {                          \
            const int mi = (S - 1) >> 1, rg = ((S - 1) & 1) * 2 + (k >> 2);      \
            const int ni = k & 3;                                                \
            int grow = g0 + wr * 64 + mi * 16 + ((l >> 4) & 3) * 4 + rg;         \
            int c = col0 + nt * 128 + wc * 64 + ni * 16 + (l & 15);              \
            pm[mi * 16 + rg * 4 + ni] =                                          \
                __builtin_nontemporal_load(mask + (size_t)grow * 4096 + c);      \
        }                                                                        \
    }                                                                            \
    if (S <= 7) {                                                                \
        const f32x4 z = (f32x4){0.f, 0.f, 0.f, 0.f};                             \
        f32x4* zp = reinterpret_cast<f32x4*>(                                    \
            out + (size_t)(g0 + nt * 16 + S * 2) * 4096 + col0);                 \
        __builtin_nontemporal_store(z, zp + tid);                                \
        __builtin_nontemporal_store(z, zp + 1024 + tid);                         \
    }                                                                            \
    /* ---- slot4: counted wait + barrier ---- */                                \
    if (S >= 10 && last) { if (S == 10) { WAITVM(0); } }                         \
    else                 { WAITVM(IS); }                                         \
    if (!(S == 11 && last)) __builtin_amdgcn_s_barrier();                        \
} while (0)

    for (int nt = 0; nt < 8; ++nt) {
        const bool last = (nt == 7);
        PHASE(0, 10);
        PHASE(1, 18);
        PHASE(2, 18);
        PHASE(3, 18);
        PHASE(4, 18);
        PHASE(5, 10);
        PHASE(6, 10);
        PHASE(7, 10);
        PHASE(8, 8);
        PHASE(9, 8);
        PHASE(10, 8);
        PHASE(11, 8);
    }
#undef PHASE
#undef SA_
#undef SB_

    // ---- reduce across 16 col-lanes, then 2 col-waves ----
    #pragma unroll
    for (int off = 1; off < 16; off <<= 1) {
        #pragma unroll
        for (int q = 0; q < 16; ++q) {
            float ov = __shfl_xor(bv[q], off);
            int   oi = __shfl_xor(bi[q], off);
            if (ov < bv[q] || (ov == bv[q] && oi < bi[q])) { bv[q] = ov; bi[q] = oi; }
        }
    }
    if ((l & 15) == 0) {
        #pragma unroll
        for (int mi = 0; mi < 4; ++mi)
            #pragma unroll
            for (int rg = 0; rg < 4; ++rg) {
                int rowl = wr * 64 + mi * 16 + ((l >> 4) & 3) * 4 + rg;
                candv[rowl][wc] = bv[mi * 4 + rg];
                candi[rowl][wc] = bi[mi * 4 + rg];
            }
    }
    __syncthreads();
    if (tid < 128) {
        float v  = candv[tid][0];
        int   ix = candi[tid][0];
        float v2 = candv[tid][1];
        int   i2 = candi[tid][1];
        if (v2 < v || (v2 == v && i2 < ix)) { v = v2; ix = i2; }
        int grow = g0 + tid;
        pv[grow * 4 + cq] = v;
        pi[grow * 4 + cq] = ix;
    }
}

__global__ __launch_bounds__(256) void k_fin(const float* __restrict__ pv,
                                             const int* __restrict__ pi,
                                             float* __restrict__ out) {
    int t = blockIdx.x * 256 + threadIdx.x;
    float v  = pv[t * 4];
    int   ix = pi[t * 4];
    #pragma unroll
    for (int q = 1; q < 4; ++q) {
        float v2 = pv[t * 4 + q];
        int   i2 = pi[t * 4 + q];
        if (v2 < v || (v2 == v && i2 < ix)) { v = v2; ix = i2; }
    }
    out[67108864 + t]         = (float)ix;
    out[67108864 + 16384 + t] = v;
    out[(size_t)t * 4096 + (size_t)ix] = 1.0f;
}

// ================= fallback path (needs only 384 KB ws) =================
__global__ __launch_bounds__(256) void k_rowsq(const float* __restrict__ xd,
                                               const float* __restrict__ yd,
                                               float* __restrict__ ws) {
    int tid  = threadIdx.x;
    int wid  = tid >> 6, lane = tid & 63;
    int gr   = blockIdx.x * 4 + wid;
    const float* src = (gr < 16384) ? (xd + (size_t)gr * 128)
                                    : (yd + (size_t)(gr - 16384) * 128);
    float2 v = reinterpret_cast<const float2*>(src)[lane];
    float s  = v.x * v.x + v.y * v.y;
    for (int off = 32; off > 0; off >>= 1) s += __shfl_down(s, off);
    if (lane == 0) ws[gr] = s;
}

__global__ __launch_bounds__(256, 1) void k_main_fb(const float* __restrict__ xd,
                                                    const float* __restrict__ yd,
                                                    const float* __restrict__ mask,
                                                    const float* __restrict__ ws,
                                                    float* __restrict__ pvals,
                                                    int* __restrict__ pidx,
                                                    float* __restrict__ mm) {
    __shared__ __align__(16) float Xs[128 * 128];
    __shared__ __align__(16) float Ys[128 * 128];
    const int bid  = blockIdx.x;
    const int mh   = bid & 1;
    const int rb   = (bid >> 1) & 31;
    const int b    = bid >> 6;
    const int tid  = threadIdx.x;
    const int ty   = tid >> 4;
    const int tx   = tid & 15;
    const int row0 = rb * 128;
    const int m0   = mh * 2048;
    {
        const float4 z = make_float4(0.f, 0.f, 0.f, 0.f);
        size_t base = ((size_t)(b * 4096 + row0)) * 4096 + (size_t)m0;
        for (int r = 0; r < 128; ++r) {
            float4* p = reinterpret_cast<float4*>(mm + base + (size_t)r * 4096);
            p[tid] = z; p[tid + 256] = z;
        }
    }
    {
        int lrow = tid >> 5, slot = tid & 31;
        for (int p = 0; p < 16; ++p) {
            int row  = p * 8 + lrow;
            float4 v = reinterpret_cast<const float4*>(
                           xd + ((size_t)(b * 4096 + row0 + row)) * 128)[slot];
            int ss = slot ^ (row & 31);
            *reinterpret_cast<float4*>(&Xs[row * 128 + (ss << 2)]) = v;
        }
    }
    float x2r[8];
    #pragma unroll
    for (int i = 0; i < 8; ++i) x2r[i] = ws[b * 4096 + row0 + ty * 8 + i];
    const float* y2g = ws + 16384 + b * 4096;
    float bv[8]; int bi[8];
    #pragma unroll
    for (int i = 0; i < 8; ++i) { bv[i] = 3.4e38f; bi[i] = 0; }
    __syncthreads();
    for (int tile = 0; tile < 16; ++tile) {
        const int mbase = m0 + tile * 128;
        {
            int lrow = tid >> 5, slot = tid & 31;
            for (int p = 0; p < 16; ++p) {
                int row  = p * 8 + lrow;
                float4 v = reinterpret_cast<const float4*>(
                               yd + ((size_t)(b * 4096 + mbase + row)) * 128)[slot];
                int ss = slot ^ (row & 31);
                *reinterpret_cast<float4*>(&Ys[row * 128 + (ss << 2)]) = v;
            }
        }
        __syncthreads();
        float acc[8][8];
        #pragma unroll
        for (int i = 0; i < 8; ++i)
            #pragma unroll
            for (int jj = 0; jj < 8; ++jj) acc[i][jj] = 0.0f;
        #pragma unroll 4
        for (int ks = 0; ks < 32; ++ks) {
            float4 bf[8];
            #pragma unroll
            for (int jj = 0; jj < 8; ++jj) {
                int c = jj * 16 + tx;
                bf[jj] = *reinterpret_cast<const float4*>(&Ys[c * 128 + ((ks ^ (c & 31)) << 2)]);
            }
            #pragma unroll
            for (int i = 0; i < 8; ++i) {
                int r = ty * 8 + i;
                float4 a = *reinterpret_cast<const float4*>(&Xs[r * 128 + ((ks ^ (r & 31)) << 2)]);
                #pragma unroll
                for (int jj = 0; jj < 8; ++jj) {
                    acc[i][jj] = fmaf(a.x, bf[jj].x, acc[i][jj]);
                    acc[i][jj] = fmaf(a.y, bf[jj].y, acc[i][jj]);
                    acc[i][jj] = fmaf(a.z, bf[jj].z, acc[i][jj]);
                    acc[i][jj] = fmaf(a.w, bf[jj].w, acc[i][jj]);
                }
            }
        }
        float y2v[8];
        #pragma unroll
        for (int jj = 0; jj < 8; ++jj) y2v[jj] = y2g[mbase + jj * 16 + tx];
        #pragma unroll
        for (int i = 0; i < 8; ++i) {
            int r = ty * 8 + i;
            const float* mr = mask + ((size_t)(b * 4096 + row0 + r)) * 4096;
            #pragma unroll
            for (int jj = 0; jj < 8; ++jj) {
                int   m  = mbase + jj * 16 + tx;
                float d2 = x2r[i] + y2v[jj] - 2.0f * acc[i][jj];
                float d  = sqrtf(fmaxf(d2, 0.0f)) * mr[m];
                if (d < bv[i]) { bv[i] = d; bi[i] = m; }
            }
        }
        __syncthreads();
    }
    float* candv = Xs;
    int*   candi = reinterpret_cast<int*>(Xs + 2048);
    #pragma unroll
    for (int i = 0; i < 8; ++i) {
        int r = ty * 8 + i;
        candv[r * 16 + tx] = bv[i];
        candi[r * 16 + tx] = bi[i];
    }
    __syncthreads();
    if (tid < 128) {
        int   r  = tid;
        float v  = candv[r * 16];
        int   ix = candi[r * 16];
        for (int t = 1; t < 16; ++t) {
            float v2 = candv[r * 16 + t];
            int   i2 = candi[r * 16 + t];
            if (v2 < v || (v2 == v && i2 < ix)) { v = v2; ix = i2; }
        }
        int grow = b * 4096 + row0 + r;
        pvals[grow * 2 + mh] = v;
        pidx [grow * 2 + mh] = ix;
    }
}

__global__ __launch_bounds__(256) void k_fin_fb(const float* __restrict__ pvals,
                                                const int* __restrict__ pidx,
                                                float* __restrict__ out) {
    int t = blockIdx.x * 256 + threadIdx.x;
    float v0 = pvals[t * 2], v1 = pvals[t * 2 + 1];
    int   i0 = pidx [t * 2], i1 = pidx [t * 2 + 1];
    bool take1 = (v1 < v0) || (v1 == v0 && i1 < i0);
    float v  = take1 ? v1 : v0;
    int   ix = take1 ? i1 : i0;
    out[67108864 + t]         = (float)ix;
    out[67108864 + 16384 + t] = v;
    out[(size_t)t * 4096 + (size_t)ix] = 1.0f;
}

extern "C" void kernel_launch(void* const* d_in, const int* in_sizes, int n_in,
                              void* d_out, int out_size, void* d_ws, size_t ws_size,
                              hipStream_t stream) {
    const float* xd   = (const float*)d_in[0];
    const float* yd   = (const float*)d_in[1];
    const float* mask = (const float*)d_in[2];
    float* out = (float*)d_out;
    float* wsf = (float*)d_ws;

    const size_t need = 131072 + 6 * PS * 2 + 524288;   // 25,821,184
    if (ws_size >= need) {
        unsigned short* pl = (unsigned short*)((char*)d_ws + 131072);
        float* pv = (float*)((char*)d_ws + 131072 + 6 * PS * 2);
        int*   pi = (int*)  ((char*)d_ws + 131072 + 6 * PS * 2 + 262144);
        k_prep <<<2048, 256, 0, stream>>>(xd, yd, pl, wsf);
        k_gemm <<<512,  256, 0, stream>>>(mask, wsf, pl, out, pv, pi);
        k_fin  <<<64,   256, 0, stream>>>(pv, pi, out);
    } else {
        float* pvals = wsf + 32768;
        int*   pidx  = (int*)(wsf + 65536);
        k_rowsq  <<<8192, 256, 0, stream>>>(xd, yd, wsf);
        k_main_fb<<<256,  256, 0, stream>>>(xd, yd, mask, wsf, pvals, pidx, out);
        k_fin_fb <<<64,   256, 0, stream>>>(pvals, pidx, out);
    }
}

// Round 6
// 202.111 us; speedup vs baseline: 5.9943x; 5.9943x over previous
//
#include <hip/hip_runtime.h>

// B=4, N=M=4096, D=128.
// d_out (floats): match_mask [4*4096*4096] | pairs [16384] (as float) | top_dists [16384]
// ws fast path:
//   bytes [0, 131072):        x2 [16384] f32 | y2 [16384] f32
//   bytes [131072, 25296896): planes, 6 x PS elems bf16 (x:h,m,l then y:h,m,l)
//     chunk layout: [b(4)][kh(2)][tile(32)] -> 8192-elem (16 KiB) chunk
//     within chunk: [rb(8)][kc(2)][lane(64)][e(8)], value = in[b][tile*128+rb*16+(l&15)][kh*64+kc*32+(l>>4)*8+e]
//   then pv [16384*2] f32 | pi [16384*2] i32
// Products needed: hh, hm, mh, mm, hl, lh (A-plane x B-plane).
// Schedule: A planes resident in LDS; B streams one (plane,kh) chunk per phase:
//   B=h -> A{h,m,l}; B=m -> A{h,m}; B=l -> A{h}.

typedef float  f32x4  __attribute__((ext_vector_type(4)));
typedef short  bf16x8 __attribute__((ext_vector_type(8)));

#define PS ((size_t)2097152)

#define WAITVM_(N) asm volatile("s_waitcnt vmcnt(" #N ")" ::: "memory")
#define WAITVM(N)  WAITVM_(N)
#define BAR        __builtin_amdgcn_s_barrier()

__device__ __forceinline__ unsigned short f2bf(float x) {
    unsigned u = __float_as_uint(x);
    u += 0x7FFFu + ((u >> 16) & 1u);
    return (unsigned short)(u >> 16);
}
__device__ __forceinline__ float bf2f(unsigned short s) {
    return __uint_as_float(((unsigned)s) << 16);
}
__device__ __forceinline__ void gload_lds16(const void* g, void* l) {
    __builtin_amdgcn_global_load_lds(
        (const __attribute__((address_space(1))) void*)g,
        (__attribute__((address_space(3))) void*)l, 16, 0, 0);
}

// ---- split f32 -> 3 bf16 planes (fragment order) + fused row sum-of-squares ----
__global__ __launch_bounds__(256) void k_prep(const float* __restrict__ xd,
                                              const float* __restrict__ yd,
                                              unsigned short* __restrict__ pl,
                                              float* __restrict__ ws) {
    __shared__ float sm[4][16];
    int bid  = blockIdx.x;            // 0..2047
    int i    = bid >> 10;
    int b    = (bid >> 8) & 3;
    int rblk = bid & 255;
    int tid  = threadIdx.x;
    int kb   = tid >> 6;
    int l    = tid & 63;
    int r    = rblk * 16 + (l & 15);
    int k0   = kb * 32 + ((l >> 4) & 3) * 8;
    const float* src = (i ? yd : xd) + ((size_t)(b * 4096 + r) * 128 + k0);
    float v[8];
    *reinterpret_cast<float4*>(v)     = *reinterpret_cast<const float4*>(src);
    *reinterpret_cast<float4*>(v + 4) = *reinterpret_cast<const float4*>(src + 4);
    bf16x8 hv, mv, lv;
    float s = 0.f;
    #pragma unroll
    for (int e = 0; e < 8; ++e) {
        float x = v[e];
        s = fmaf(x, x, s);
        unsigned short h  = f2bf(x);
        float r1 = x - bf2f(h);
        unsigned short m  = f2bf(r1);
        float r2 = r1 - bf2f(m);
        unsigned short lo = f2bf(r2);
        hv[e] = (short)h; mv[e] = (short)m; lv[e] = (short)lo;
    }
    int rt = rblk >> 3, rb = rblk & 7, kh = kb >> 1, kc = kb & 1;
    size_t base = ((((size_t)((b * 2 + kh) * 32 + rt)) * 8 + rb) * 2 + kc) * 512 + (size_t)l * 8;
    unsigned short* dst = pl + (size_t)(i * 3) * PS;
    *reinterpret_cast<bf16x8*>(dst + base)          = hv;
    *reinterpret_cast<bf16x8*>(dst + base + PS)     = mv;
    *reinterpret_cast<bf16x8*>(dst + base + 2 * PS) = lv;
    s += __shfl_xor(s, 16);
    s += __shfl_xor(s, 32);
    if (l < 16) sm[kb][l] = s;
    __syncthreads();
    if (tid < 16) {
        float t = sm[0][tid] + sm[1][tid] + sm[2][tid] + sm[3][tid];
        ws[(i ? 16384 : 0) + b * 4096 + rblk * 16 + tid] = t;
    }
}

// ---- main: A-resident-LDS, B-streamed counted-vmcnt pipeline, fused epilogue ----
__global__ __launch_bounds__(512, 2) void k_gemm(const float* __restrict__ mask,
                                                 const float* __restrict__ ws,
                                                 const unsigned short* __restrict__ pl,
                                                 float* __restrict__ out,
                                                 float* __restrict__ pv,
                                                 int* __restrict__ pi) {
    __shared__ __align__(16) unsigned short Ab[2][3][8192];  // 96 KiB resident A
    __shared__ __align__(16) unsigned short Bs[3][8192];     // 48 KiB B slots
    __shared__ __align__(16) float y2s[2048];                // 8 KiB
    __shared__ float candv[128][4];
    __shared__ int   candi[128][4];

    const int bid = blockIdx.x;        // 256 blocks = 1/CU
    const int xcd = bid & 7;
    const int b   = xcd >> 1;          // batch pinned per XCD pair
    const int ch  = xcd & 1;           // col half (2048 cols)
    const int rt  = bid >> 3;          // row tile 0..31
    const int tid = threadIdx.x;
    const int w   = tid >> 6, l = tid & 63;
    const int wr  = w >> 2, wc = w & 3;     // 2x4 waves: 64 rows x 32 cols each
    const int lg4 = (l >> 4) & 3, l15 = l & 15;
    const int g0  = b * 4096 + rt * 128;

    // x2 for this thread's 16 rows (L2-hot; issued first so prologue WAITVM retires them)
    float x2r[16];
    #pragma unroll
    for (int mi = 0; mi < 4; ++mi)
        #pragma unroll
        for (int rg = 0; rg < 4; ++rg)
            x2r[mi * 4 + rg] = ws[g0 + wr * 64 + mi * 16 + lg4 * 4 + rg];

    // ---- prologue staging: A (12), y2 (1), B c0 (2), B c1 (2) ----
    #pragma unroll
    for (int c = 0; c < 6; ++c) {
        const int kh = c / 3, ap = c % 3;
        const unsigned short* Ac = pl + (size_t)ap * PS
            + (((size_t)((b * 2 + kh) * 32 + rt)) << 13);
        const char* g = (const char*)Ac + w * 1024 + l * 16;
        char* dd = (char*)(&Ab[kh][ap][0]) + w * 1024;
        gload_lds16(g, dd);
        gload_lds16(g + 8192, dd + 8192);
    }
    {
        const char* g = (const char*)(ws + 16384 + b * 4096 + ch * 2048) + w * 1024 + l * 16;
        gload_lds16(g, (char*)y2s + w * 1024);
    }

#define STAGE_B(NTT, CC, SLOT) do {                                               \
    const int kh_ = (CC) / 3, bp_ = (CC) % 3;                                     \
    const unsigned short* Bc_ = pl + (size_t)(3 + bp_) * PS                       \
        + (((size_t)((b * 2 + kh_) * 32 + (ch * 16 + (NTT)))) << 13);             \
    const char* g_ = (const char*)Bc_ + w * 1024 + l * 16;                        \
    char* d_ = (char*)(&Bs[SLOT][0]) + w * 1024;                                  \
    gload_lds16(g_, d_);                                                          \
    gload_lds16(g_ + 8192, d_ + 8192);                                            \
} while (0)

    STAGE_B(0, 0, 0);
    STAGE_B(0, 1, 1);
    WAITVM(2);
    BAR;

    float bv[16];
    int   bi[16];
    #pragma unroll
    for (int q = 0; q < 16; ++q) { bv[q] = 3.4e38f; bi[q] = 0; }

    f32x4 acc[4][2];
    float pm[32];

#define MLOAD(K) do {                                                             \
    const int mi_ = (K) >> 3, rg_ = ((K) >> 1) & 3, ni_ = (K) & 1;                \
    pm[K] = mask[(size_t)(g0 + wr * 64 + mi_ * 16 + lg4 * 4 + rg_) * 4096         \
                 + (ch * 2048 + nt * 128 + wc * 32 + ni_ * 16 + l15)];            \
} while (0)

#define ZST(I) do {                                                               \
    const f32x4 z_ = (f32x4){0.f, 0.f, 0.f, 0.f};                                 \
    const int r_ = (tid >> 5) * 8 + (I);                                          \
    *reinterpret_cast<f32x4*>(out + (size_t)(g0 + r_) * 4096                      \
        + ch * 2048 + nt * 128 + ((tid & 31) << 2)) = z_;                         \
} while (0)

#define COMPUTE(CC, SLOT) do {                                                    \
    const int kh_ = (CC) / 3, bp_ = (CC) % 3;                                     \
    const int lim_ = (bp_ == 0) ? 2 : (bp_ == 1) ? 1 : 0;                         \
    bf16x8 bfr_[2][2];                                                            \
    _Pragma("unroll") for (int ni = 0; ni < 2; ++ni)                              \
    _Pragma("unroll") for (int kc = 0; kc < 2; ++kc)                              \
        bfr_[ni][kc] = *reinterpret_cast<const bf16x8*>(                          \
            &Bs[SLOT][(((wc * 2 + ni) * 2 + kc) << 9) + l * 8]);                  \
    __builtin_amdgcn_s_setprio(1);                                                \
    _Pragma("unroll") for (int ap = 0; ap < 3; ++ap) {                            \
        if (ap <= lim_) {                                                         \
            _Pragma("unroll") for (int mi = 0; mi < 4; ++mi) {                    \
                _Pragma("unroll") for (int kc = 0; kc < 2; ++kc) {                \
                    bf16x8 af_ = *reinterpret_cast<const bf16x8*>(                \
                        &Ab[kh_][ap][(((wr * 4 + mi) * 2 + kc) << 9) + l * 8]);   \
                    _Pragma("unroll") for (int ni = 0; ni < 2; ++ni)              \
                        acc[mi][ni] = __builtin_amdgcn_mfma_f32_16x16x32_bf16(    \
                            af_, bfr_[ni][kc], acc[mi][ni], 0, 0, 0);             \
                }                                                                 \
            }                                                                     \
        }                                                                         \
    }                                                                             \
    __builtin_amdgcn_s_setprio(0);                                                \
} while (0)

    for (int nt = 0; nt < 16; ++nt) {
        const int ntn = (nt < 15) ? nt + 1 : 15;
        #pragma unroll
        for (int mi = 0; mi < 4; ++mi)
            #pragma unroll
            for (int ni = 0; ni < 2; ++ni) acc[mi][ni] = (f32x4){0.f, 0.f, 0.f, 0.f};

        // PHASE 0: compute c0(slot0); stage c2->slot2
        STAGE_B(nt, 2, 2);
        MLOAD(0); MLOAD(1); MLOAD(2); MLOAD(3); MLOAD(4); MLOAD(5);
        ZST(0); ZST(1);
        COMPUTE(0, 0);
        WAITVM(10); BAR;
        // PHASE 1: compute c1(slot1); stage c3->slot0
        STAGE_B(nt, 3, 0);
        MLOAD(6); MLOAD(7); MLOAD(8); MLOAD(9); MLOAD(10); MLOAD(11);
        ZST(2); ZST(3);
        COMPUTE(1, 1);
        WAITVM(18); BAR;
        // PHASE 2: compute c2(slot2); stage c4->slot1
        STAGE_B(nt, 4, 1);
        MLOAD(12); MLOAD(13); MLOAD(14); MLOAD(15); MLOAD(16); MLOAD(17);
        ZST(4);
        COMPUTE(2, 2);
        WAITVM(17); BAR;
        // PHASE 3: compute c3(slot0); stage c5->slot2
        STAGE_B(nt, 5, 2);
        MLOAD(18); MLOAD(19); MLOAD(20); MLOAD(21); MLOAD(22); MLOAD(23);
        ZST(5);
        COMPUTE(3, 0);
        WAITVM(16); BAR;
        // PHASE 4: compute c4(slot1); stage next c0->slot0
        STAGE_B(ntn, 0, 0);
        MLOAD(24); MLOAD(25); MLOAD(26); MLOAD(27);
        ZST(6);
        COMPUTE(4, 1);
        WAITVM(14); BAR;
        // PHASE 5: compute c5(slot2); masks BEFORE stage so epilogue can wait vmcnt(3)
        MLOAD(28); MLOAD(29); MLOAD(30); MLOAD(31);
        STAGE_B(ntn, 1, 1);
        ZST(7);
        COMPUTE(5, 2);
        WAITVM(12); BAR;

        // EPILOGUE: all 32 masks retired (only next-stage(2)+zero(1) may remain)
        WAITVM(3);
        #pragma unroll
        for (int ni = 0; ni < 2; ++ni) {
            const int c = ch * 2048 + nt * 128 + wc * 32 + ni * 16 + l15;
            float y2v = y2s[nt * 128 + wc * 32 + ni * 16 + l15];
            #pragma unroll
            for (int mi = 0; mi < 4; ++mi) {
                #pragma unroll
                for (int rg = 0; rg < 4; ++rg) {
                    float d2 = x2r[mi * 4 + rg] + y2v - 2.0f * acc[mi][ni][rg];
                    float d  = sqrtf(fmaxf(d2, 0.0f)) * pm[mi * 8 + rg * 2 + ni];
                    const int q = mi * 4 + rg;
                    if (d < bv[q]) { bv[q] = d; bi[q] = c; }
                }
            }
        }
    }
#undef STAGE_B
#undef MLOAD
#undef ZST
#undef COMPUTE

    // ---- reduce across 16 col-lanes, then 4 col-waves ----
    #pragma unroll
    for (int off = 1; off < 16; off <<= 1) {
        #pragma unroll
        for (int q = 0; q < 16; ++q) {
            float ov = __shfl_xor(bv[q], off);
            int   oi = __shfl_xor(bi[q], off);
            if (ov < bv[q] || (ov == bv[q] && oi < bi[q])) { bv[q] = ov; bi[q] = oi; }
        }
    }
    if (l15 == 0) {
        #pragma unroll
        for (int mi = 0; mi < 4; ++mi)
            #pragma unroll
            for (int rg = 0; rg < 4; ++rg) {
                int rowl = wr * 64 + mi * 16 + lg4 * 4 + rg;
                candv[rowl][wc] = bv[mi * 4 + rg];
                candi[rowl][wc] = bi[mi * 4 + rg];
            }
    }
    __syncthreads();
    if (tid < 128) {
        float v  = candv[tid][0];
        int   ix = candi[tid][0];
        #pragma unroll
        for (int t = 1; t < 4; ++t) {
            float v2 = candv[tid][t];
            int   i2 = candi[tid][t];
            if (v2 < v || (v2 == v && i2 < ix)) { v = v2; ix = i2; }
        }
        int grow = g0 + tid;
        pv[grow * 2 + ch] = v;
        pi[grow * 2 + ch] = ix;
    }
}

__global__ __launch_bounds__(256) void k_fin(const float* __restrict__ pv,
                                             const int* __restrict__ pi,
                                             float* __restrict__ out) {
    int t = blockIdx.x * 256 + threadIdx.x;   // row 0..16383
    float v0 = pv[t * 2], v1 = pv[t * 2 + 1];
    int   i0 = pi[t * 2], i1 = pi[t * 2 + 1];
    bool take1 = (v1 < v0) || (v1 == v0 && i1 < i0);
    float v  = take1 ? v1 : v0;
    int   ix = take1 ? i1 : i0;
    out[67108864 + t]         = (float)ix;            // pairs
    out[67108864 + 16384 + t] = v;                    // top_dists
    out[(size_t)t * 4096 + (size_t)ix] = 1.0f;        // one-hot
}

// ================= fallback path (needs only 384 KB ws) =================
__global__ __launch_bounds__(256) void k_rowsq(const float* __restrict__ xd,
                                               const float* __restrict__ yd,
                                               float* __restrict__ ws) {
    int tid  = threadIdx.x;
    int wid  = tid >> 6, lane = tid & 63;
    int gr   = blockIdx.x * 4 + wid;
    const float* src = (gr < 16384) ? (xd + (size_t)gr * 128)
                                    : (yd + (size_t)(gr - 16384) * 128);
    float2 v = reinterpret_cast<const float2*>(src)[lane];
    float s  = v.x * v.x + v.y * v.y;
    for (int off = 32; off > 0; off >>= 1) s += __shfl_down(s, off);
    if (lane == 0) ws[gr] = s;
}

__global__ __launch_bounds__(256, 1) void k_main_fb(const float* __restrict__ xd,
                                                    const float* __restrict__ yd,
                                                    const float* __restrict__ mask,
                                                    const float* __restrict__ ws,
                                                    float* __restrict__ pvals,
                                                    int* __restrict__ pidx,
                                                    float* __restrict__ mm) {
    __shared__ __align__(16) float Xs[128 * 128];
    __shared__ __align__(16) float Ys[128 * 128];
    const int bid  = blockIdx.x;
    const int mh   = bid & 1;
    const int rb   = (bid >> 1) & 31;
    const int b    = bid >> 6;
    const int tid  = threadIdx.x;
    const int ty   = tid >> 4;
    const int tx   = tid & 15;
    const int row0 = rb * 128;
    const int m0   = mh * 2048;
    {
        const float4 z = make_float4(0.f, 0.f, 0.f, 0.f);
        size_t base = ((size_t)(b * 4096 + row0)) * 4096 + (size_t)m0;
        for (int r = 0; r < 128; ++r) {
            float4* p = reinterpret_cast<float4*>(mm + base + (size_t)r * 4096);
            p[tid] = z; p[tid + 256] = z;
        }
    }
    {
        int lrow = tid >> 5, slot = tid & 31;
        for (int p = 0; p < 16; ++p) {
            int row  = p * 8 + lrow;
            float4 v = reinterpret_cast<const float4*>(
                           xd + ((size_t)(b * 4096 + row0 + row)) * 128)[slot];
            int ss = slot ^ (row & 31);
            *reinterpret_cast<float4*>(&Xs[row * 128 + (ss << 2)]) = v;
        }
    }
    float x2r[8];
    #pragma unroll
    for (int i = 0; i < 8; ++i) x2r[i] = ws[b * 4096 + row0 + ty * 8 + i];
    const float* y2g = ws + 16384 + b * 4096;
    float bv[8]; int bi[8];
    #pragma unroll
    for (int i = 0; i < 8; ++i) { bv[i] = 3.4e38f; bi[i] = 0; }
    __syncthreads();
    for (int tile = 0; tile < 16; ++tile) {
        const int mbase = m0 + tile * 128;
        {
            int lrow = tid >> 5, slot = tid & 31;
            for (int p = 0; p < 16; ++p) {
                int row  = p * 8 + lrow;
                float4 v = reinterpret_cast<const float4*>(
                               yd + ((size_t)(b * 4096 + mbase + row)) * 128)[slot];
                int ss = slot ^ (row & 31);
                *reinterpret_cast<float4*>(&Ys[row * 128 + (ss << 2)]) = v;
            }
        }
        __syncthreads();
        float acc[8][8];
        #pragma unroll
        for (int i = 0; i < 8; ++i)
            #pragma unroll
            for (int jj = 0; jj < 8; ++jj) acc[i][jj] = 0.0f;
        #pragma unroll 4
        for (int ks = 0; ks < 32; ++ks) {
            float4 bf[8];
            #pragma unroll
            for (int jj = 0; jj < 8; ++jj) {
                int c = jj * 16 + tx;
                bf[jj] = *reinterpret_cast<const float4*>(&Ys[c * 128 + ((ks ^ (c & 31)) << 2)]);
            }
            #pragma unroll
            for (int i = 0; i < 8; ++i) {
                int r = ty * 8 + i;
                float4 a = *reinterpret_cast<const float4*>(&Xs[r * 128 + ((ks ^ (r & 31)) << 2)]);
                #pragma unroll
                for (int jj = 0; jj < 8; ++jj) {
                    acc[i][jj] = fmaf(a.x, bf[jj].x, acc[i][jj]);
                    acc[i][jj] = fmaf(a.y, bf[jj].y, acc[i][jj]);
                    acc[i][jj] = fmaf(a.z, bf[jj].z, acc[i][jj]);
                    acc[i][jj] = fmaf(a.w, bf[jj].w, acc[i][jj]);
                }
            }
        }
        float y2v[8];
        #pragma unroll
        for (int jj = 0; jj < 8; ++jj) y2v[jj] = y2g[mbase + jj * 16 + tx];
        #pragma unroll
        for (int i = 0; i < 8; ++i) {
            int r = ty * 8 + i;
            const float* mr = mask + ((size_t)(b * 4096 + row0 + r)) * 4096;
            #pragma unroll
            for (int jj = 0; jj < 8; ++jj) {
                int   m  = mbase + jj * 16 + tx;
                float d2 = x2r[i] + y2v[jj] - 2.0f * acc[i][jj];
                float d  = sqrtf(fmaxf(d2, 0.0f)) * mr[m];
                if (d < bv[i]) { bv[i] = d; bi[i] = m; }
            }
        }
        __syncthreads();
    }
    float* candv = Xs;
    int*   candi = reinterpret_cast<int*>(Xs + 2048);
    #pragma unroll
    for (int i = 0; i < 8; ++i) {
        int r = ty * 8 + i;
        candv[r * 16 + tx] = bv[i];
        candi[r * 16 + tx] = bi[i];
    }
    __syncthreads();
    if (tid < 128) {
        int   r  = tid;
        float v  = candv[r * 16];
        int   ix = candi[r * 16];
        for (int t = 1; t < 16; ++t) {
            float v2 = candv[r * 16 + t];
            int   i2 = candi[r * 16 + t];
            if (v2 < v || (v2 == v && i2 < ix)) { v = v2; ix = i2; }
        }
        int grow = b * 4096 + row0 + r;
        pvals[grow * 2 + mh] = v;
        pidx [grow * 2 + mh] = ix;
    }
}

__global__ __launch_bounds__(256) void k_fin_fb(const float* __restrict__ pvals,
                                                const int* __restrict__ pidx,
                                                float* __restrict__ out) {
    int t = blockIdx.x * 256 + threadIdx.x;
    float v0 = pvals[t * 2], v1 = pvals[t * 2 + 1];
    int   i0 = pidx [t * 2], i1 = pidx [t * 2 + 1];
    bool take1 = (v1 < v0) || (v1 == v0 && i1 < i0);
    float v  = take1 ? v1 : v0;
    int   ix = take1 ? i1 : i0;
    out[67108864 + t]         = (float)ix;
    out[67108864 + 16384 + t] = v;
    out[(size_t)t * 4096 + (size_t)ix] = 1.0f;
}

extern "C" void kernel_launch(void* const* d_in, const int* in_sizes, int n_in,
                              void* d_out, int out_size, void* d_ws, size_t ws_size,
                              hipStream_t stream) {
    const float* xd   = (const float*)d_in[0];
    const float* yd   = (const float*)d_in[1];
    const float* mask = (const float*)d_in[2];
    float* out = (float*)d_out;
    float* wsf = (float*)d_ws;

    const size_t need = 131072 + 6 * PS * 2 + 262144;   // 25,559,040
    if (ws_size >= need) {
        unsigned short* pl = (unsigned short*)((char*)d_ws + 131072);
        float* pv = (float*)((char*)d_ws + 131072 + 6 * PS * 2);
        int*   pi = (int*)  ((char*)d_ws + 131072 + 6 * PS * 2 + 131072);
        k_prep <<<2048, 256, 0, stream>>>(xd, yd, pl, wsf);
        k_gemm <<<256,  512, 0, stream>>>(mask, wsf, pl, out, pv, pi);
        k_fin  <<<64,   256, 0, stream>>>(pv, pi, out);
    } else {
        float* pvals = wsf + 32768;
        int*   pidx  = (int*)(wsf + 65536);
        k_rowsq  <<<8192, 256, 0, stream>>>(xd, yd, wsf);
        k_main_fb<<<256,  256, 0, stream>>>(xd, yd, mask, wsf, pvals, pidx, out);
        k_fin_fb <<<64,   256, 0, stream>>>(pvals, pidx, out);
    }
}